// Round 8
// baseline (477.571 us; speedup 1.0000x reference)
//
#include <hip/hip_runtime.h>
#include <hip/hip_bf16.h>
#include <hip/hip_fp16.h>

#define N_Q 10000
#define D_MODEL 256
#define NH 8
#define PT 4
#define PP 4
#define PS 4
#define DFF 1024
#define NC 6
#define HF 24
#define WF 60
#define BH 100
#define BW 100
#define T_RAD 0.15f
#define S_RAD 0.12f

typedef __hip_bfloat16 bf16;
typedef __half elt;                 // internal storage type: f16 (enables v_pk_fma_f16)
typedef _Float16 __attribute__((ext_vector_type(8))) half8;
typedef __attribute__((ext_vector_type(4))) float f32x4;

__device__ __forceinline__ float h2f(elt v) { return __half2float(v); }
__device__ __forceinline__ elt f2h(float v) { return __float2half(v); }

__device__ __forceinline__ f32x4 mfma16(half8 a, half8 b, f32x4 c) {
    return __builtin_amdgcn_mfma_f32_16x16x32_f16(a, b, c, 0, 0, 0);
}

// dtype-adaptive loads/stores for INPUT tensors; f: 0=f32, 1=bf16, 2=f16
__device__ __forceinline__ float load_any(const void* p, long i, int f) {
    if (f == 0) return ((const float*)p)[i];
    if (f == 1) return __bfloat162float(((const bf16*)p)[i]);
    return __half2float(((const __half*)p)[i]);
}
__device__ __forceinline__ void store_any(void* p, long i, int f, float v) {
    if (f == 0)      ((float*)p)[i] = v;
    else if (f == 1) ((bf16*)p)[i] = __float2bfloat16(v);
    else             ((__half*)p)[i] = __float2half(v);
}

__device__ __forceinline__ unsigned pack2(float a, float b) {
    __half2 h = __floats2half2_rn(a, b);
    return *(unsigned*)&h;
}

// 8-channel packed-f16 accumulate from one uint4: 4 x v_pk_fma_f16
__device__ __forceinline__ void pkfma8(__half2* hacc, __half2 w2, uint4 uu) {
    hacc[0] = __hfma2(*(__half2*)&uu.x, w2, hacc[0]);
    hacc[1] = __hfma2(*(__half2*)&uu.y, w2, hacc[1]);
    hacc[2] = __hfma2(*(__half2*)&uu.z, w2, hacc[2]);
    hacc[3] = __hfma2(*(__half2*)&uu.w, w2, hacc[3]);
}

// ---------------- dtype / mask-width detection (parallel) ----------------
__global__ __launch_bounds__(256) void detect_kernel(const void* __restrict__ ln1g,
                                                     const void* __restrict__ mask,
                                                     int* __restrict__ flags) {
    __shared__ int sh[6];
    int tid = threadIdx.x;
    if (tid < 6) sh[tid] = (tid == 0 || tid == 2 || tid == 4) ? 1 : 0;
    __syncthreads();
    const unsigned long long* m64 = (const unsigned long long*)mask;
    const unsigned int*       m32 = (const unsigned int*)mask;
    const unsigned short*     m16 = (const unsigned short*)mask;
    int lok8 = 1, lones8 = 0, lok4 = 1, lones4 = 0, lok2 = 1, lones2 = 0;
    for (int i = tid; i < 480; i += 256) {
        if (i < 120) {
            unsigned long long v = m64[i];
            if (v == 1ULL) lones8++; else if (v != 0ULL) lok8 = 0;
        }
        if (i < 240) {
            unsigned int v = m32[i];
            if (v == 1u || v == 0x3F800000u) lones4++; else if (v != 0u) lok4 = 0;
        }
        unsigned short v = m16[i];
        if (v == 1 || v == 0x3F80) lones2++; else if (v != 0) lok2 = 0;
    }
    atomicAnd(&sh[0], lok8); atomicAdd(&sh[1], lones8);
    atomicAnd(&sh[2], lok4); atomicAdd(&sh[3], lones4);
    atomicAnd(&sh[4], lok2); atomicAdd(&sh[5], lones2);
    __syncthreads();
    if (tid == 0) {
        unsigned short u0 = ((const unsigned short*)ln1g)[0];
        flags[0] = (u0 == 0x3F80) ? 1 : (u0 == 0x3C00 ? 2 : 0);
        int ms;
        if (sh[0] && sh[1] > 30)       ms = 8;
        else if (sh[2] && sh[3] > 60)  ms = 4;
        else if (sh[4] && sh[5] > 120) ms = 2;
        else                           ms = 1;
        flags[1] = ms;
    }
}

// ---------------- unified weight/image prep: transposes + flat cvt + img transpose ----------------
#define NP 23
struct PrepDesc {
    const void* src[NP];
    int dst_off[NP];
    int count[NP];
    int R[NP];
    int C[NP];
    int type[NP];       // 0 flat cvt, 1 transpose, 2 img transpose
    int blk_start[NP + 1];
};
__global__ __launch_bounds__(256) void prep_kernel(PrepDesc pd, elt* __restrict__ wgt,
                                                   elt* __restrict__ imgT,
                                                   const int* __restrict__ flags) {
    int blk = blockIdx.x;
    int a = 0;
    while (a < NP - 1 && blk >= pd.blk_start[a + 1]) a++;
    int i = (blk - pd.blk_start[a]) * 256 + threadIdx.x;
    if (i >= pd.count[a]) return;
    int f = flags[0];
    int ty = pd.type[a];
    if (ty == 0) {
        wgt[pd.dst_off[a] + i] = f2h(load_any(pd.src[a], i, f));
    } else if (ty == 1) {
        int R = pd.R[a], C = pd.C[a];
        int c = i / R, r = i % R;
        wgt[pd.dst_off[a] + i] = f2h(load_any(pd.src[a], (long)r * C + c, f));
    } else {
        int ch = i & 255;
        int t = i >> 8;
        int xx = t % WF; t /= WF;
        int yy = t % HF;
        int c  = t / HF;
        long src = (((long)(c * 256) + ch) * HF + yy) * WF + xx;
        imgT[i] = f2h(load_any(pd.src[a], src, f));
    }
}

// ---------------- LN1 over prev_bev & query, wave-per-row -> ai[N,512] ----------------
__global__ __launch_bounds__(256) void ln12_kernel(const void* __restrict__ pb,
                                                   const void* __restrict__ q,
                                                   const int* __restrict__ flags,
                                                   const elt* __restrict__ g,
                                                   const elt* __restrict__ b,
                                                   elt* __restrict__ out) {
    int wv = threadIdx.x >> 6, lane = threadIdx.x & 63;
    long row = (long)blockIdx.x * 4 + wv;
    const void* src; long r; int ooff;
    if (row < N_Q) { src = pb; r = row; ooff = 0; }
    else           { src = q;  r = row - N_Q; ooff = 256; }
    int f = flags[0];
    float v0, v1, v2, v3;
    if (f == 0) {
        float4 t = ((const float4*)src)[r * 64 + lane];
        v0 = t.x; v1 = t.y; v2 = t.z; v3 = t.w;
    } else {
        uint2 t = ((const uint2*)src)[r * 64 + lane];
        if (f == 1) {
            v0 = __uint_as_float(t.x << 16); v1 = __uint_as_float(t.x & 0xFFFF0000u);
            v2 = __uint_as_float(t.y << 16); v3 = __uint_as_float(t.y & 0xFFFF0000u);
        } else {
            __half2 h0 = *(__half2*)&t.x, h1 = *(__half2*)&t.y;
            v0 = __half2float(h0.x); v1 = __half2float(h0.y);
            v2 = __half2float(h1.x); v3 = __half2float(h1.y);
        }
    }
    float s1 = v0 + v1 + v2 + v3;
    float s2 = v0 * v0 + v1 * v1 + v2 * v2 + v3 * v3;
    #pragma unroll
    for (int m = 32; m > 0; m >>= 1) {
        s1 += __shfl_xor(s1, m);
        s2 += __shfl_xor(s2, m);
    }
    float mu = s1 * (1.f / 256.f);
    float var = s2 * (1.f / 256.f) - mu * mu;
    float inv = rsqrtf(var + 1e-5f);
    int k = lane * 4;
    float o0 = (v0 - mu) * inv * h2f(g[k+0]) + h2f(b[k+0]);
    float o1 = (v1 - mu) * inv * h2f(g[k+1]) + h2f(b[k+1]);
    float o2 = (v2 - mu) * inv * h2f(g[k+2]) + h2f(b[k+2]);
    float o3 = (v3 - mu) * inv * h2f(g[k+3]) + h2f(b[k+3]);
    uint2 st = {pack2(o0, o1), pack2(o2, o3)};
    *reinterpret_cast<uint2*>(out + r * 512 + ooff + k) = st;
}

// ---------------- LayerNorm (f32 in), wave-per-row -> f16 out ----------------
__global__ __launch_bounds__(256) void ln_kernel(const float* __restrict__ in,
                                                 const elt* __restrict__ g,
                                                 const elt* __restrict__ b,
                                                 elt* __restrict__ out) {
    int wv = threadIdx.x >> 6, lane = threadIdx.x & 63;
    long r = (long)blockIdx.x * 4 + wv;
    float4 t = ((const float4*)in)[r * 64 + lane];
    float s1 = t.x + t.y + t.z + t.w;
    float s2 = t.x * t.x + t.y * t.y + t.z * t.z + t.w * t.w;
    #pragma unroll
    for (int m = 32; m > 0; m >>= 1) {
        s1 += __shfl_xor(s1, m);
        s2 += __shfl_xor(s2, m);
    }
    float mu = s1 * (1.f / 256.f);
    float var = s2 * (1.f / 256.f) - mu * mu;
    float inv = rsqrtf(var + 1e-5f);
    int k = lane * 4;
    float o0 = (t.x - mu) * inv * h2f(g[k+0]) + h2f(b[k+0]);
    float o1 = (t.y - mu) * inv * h2f(g[k+1]) + h2f(b[k+1]);
    float o2 = (t.z - mu) * inv * h2f(g[k+2]) + h2f(b[k+2]);
    float o3 = (t.w - mu) * inv * h2f(g[k+3]) + h2f(b[k+3]);
    uint2 st = {pack2(o0, o1), pack2(o2, o3)};
    *reinterpret_cast<uint2*>(out + r * 256 + k) = st;
}

// ---------------- MFMA GEMM: out[M,J] = A @ WT^T + bias; cols split by blockIdx.y ----------------
template <int K, int J, int MODE>
__global__ __launch_bounds__(256) void gemm_mfma(const elt* __restrict__ A,
                                                 const elt* __restrict__ WT,
                                                 const elt* __restrict__ bias,
                                                 float* __restrict__ outf,
                                                 const void* __restrict__ resraw,
                                                 const float* __restrict__ resf,
                                                 const int* __restrict__ flags) {
    constexpr int LDK = K + 8;
    __shared__ elt As[32 * LDK];
    int tid = threadIdx.x;
    int row0 = blockIdx.x * 32;
    int col0 = blockIdx.y * 64;
    for (int t = tid; t < 32 * (K / 8); t += 256) {
        int r = t / (K / 8), kq = t % (K / 8);
        uint4 u = {0u, 0u, 0u, 0u};
        if (row0 + r < N_Q)
            u = *reinterpret_cast<const uint4*>(A + (size_t)(row0 + r) * K + kq * 8);
        *reinterpret_cast<uint4*>(&As[r * LDK + kq * 8]) = u;
    }
    __syncthreads();
    int wave = tid >> 6, lane = tid & 63;
    int l = lane & 15, quad = lane >> 4;
    int rh = wave >> 1, ch = wave & 1;
    constexpr int NK = K / 32;
    half8 afr[NK];
    const elt* arow = &As[(rh * 16 + l) * LDK + quad * 8];
    #pragma unroll
    for (int ks = 0; ks < NK; ks++)
        afr[ks] = *reinterpret_cast<const half8*>(arow + ks * 32);
    int fdt = flags[0];
    #pragma unroll
    for (int ct = 0; ct < 2; ct++) {
        int col = col0 + ch * 32 + ct * 16 + l;
        const elt* wrow = WT + (size_t)col * K + quad * 8;
        f32x4 acc = {0.f, 0.f, 0.f, 0.f};
        #pragma unroll
        for (int ks = 0; ks < NK; ks++) {
            half8 bfr = *reinterpret_cast<const half8*>(wrow + ks * 32);
            acc = mfma16(afr[ks], bfr, acc);
        }
        float bb = h2f(bias[col]);
        #pragma unroll
        for (int r = 0; r < 4; r++) {
            int row = row0 + rh * 16 + quad * 4 + r;
            if (row >= N_Q) continue;
            long o = (long)row * J + col;
            float v = acc[r] + bb;
            if (MODE == 2) outf[o] = v + load_any(resraw, o, fdt);
            else           outf[o] = v + resf[o];
        }
    }
}

// ---------------- Dual MFMA GEMM (concat cols J1|J2); out1=tanh*scale f16, out2 plain f16 ----
template <int K, int J1, int J2>
__global__ __launch_bounds__(256) void gemm_dual(const elt* __restrict__ A,
                                                 const elt* __restrict__ WT1,
                                                 const elt* __restrict__ b1, float scale,
                                                 elt* __restrict__ out1,
                                                 const elt* __restrict__ WT2,
                                                 const elt* __restrict__ b2,
                                                 elt* __restrict__ out2) {
    constexpr int LDK = K + 8;
    __shared__ elt As[32 * LDK];
    int tid = threadIdx.x;
    int row0 = blockIdx.x * 32;
    int col0 = blockIdx.y * 64;
    for (int t = tid; t < 32 * (K / 8); t += 256) {
        int r = t / (K / 8), kq = t % (K / 8);
        uint4 u = {0u, 0u, 0u, 0u};
        if (row0 + r < N_Q)
            u = *reinterpret_cast<const uint4*>(A + (size_t)(row0 + r) * K + kq * 8);
        *reinterpret_cast<uint4*>(&As[r * LDK + kq * 8]) = u;
    }
    __syncthreads();
    int wave = tid >> 6, lane = tid & 63;
    int l = lane & 15, quad = lane >> 4;
    int rh = wave >> 1, ch = wave & 1;
    constexpr int NK = K / 32;
    half8 afr[NK];
    const elt* arow = &As[(rh * 16 + l) * LDK + quad * 8];
    #pragma unroll
    for (int ks = 0; ks < NK; ks++)
        afr[ks] = *reinterpret_cast<const half8*>(arow + ks * 32);
    #pragma unroll
    for (int ct = 0; ct < 2; ct++) {
        int jg = col0 + ch * 32 + ct * 16 + l;
        int in1 = jg < J1;
        int cl = in1 ? jg : jg - J1;
        const elt* wrow = (in1 ? WT1 : WT2) + (size_t)cl * K + quad * 8;
        f32x4 acc = {0.f, 0.f, 0.f, 0.f};
        #pragma unroll
        for (int ks = 0; ks < NK; ks++) {
            half8 bfr = *reinterpret_cast<const half8*>(wrow + ks * 32);
            acc = mfma16(afr[ks], bfr, acc);
        }
        float bb = h2f(in1 ? b1[cl] : b2[cl]);
        #pragma unroll
        for (int r = 0; r < 4; r++) {
            int row = row0 + rh * 16 + quad * 4 + r;
            if (row >= N_Q) continue;
            float v = acc[r] + bb;
            if (in1) out1[(long)row * J1 + cl] = f2h(tanhf(v) * scale);
            else     out2[(long)row * J2 + cl] = f2h(v);
        }
    }
}

// ---------------- Fused MFMA FFN: LN3 -> @w1T,relu -> @w2T -> +x -> out ----------------
__global__ __launch_bounds__(256) void ffn_mfma(const float* __restrict__ x,
                                                const elt* __restrict__ g3,
                                                const elt* __restrict__ b3,
                                                const elt* __restrict__ w1T,
                                                const elt* __restrict__ b1,
                                                const elt* __restrict__ w2T,
                                                const elt* __restrict__ b2v,
                                                void* __restrict__ out,
                                                const int* __restrict__ flags) {
    constexpr int LDH = DFF + 8;
    constexpr int LDX = D_MODEL + 8;
    __shared__ elt hbuf[16 * LDH];
    elt* xl = hbuf;
    int tid = threadIdx.x;
    int row0 = blockIdx.x * 16;
    {
        int r = tid >> 4, lr = tid & 15;
        const float* xr = x + (long)(row0 + r) * 256 + lr * 16;
        float vals[16];
        float s1 = 0.f, s2 = 0.f;
        #pragma unroll
        for (int i = 0; i < 16; i++) {
            float v = xr[i];
            vals[i] = v; s1 += v; s2 += v * v;
        }
        #pragma unroll
        for (int off = 8; off > 0; off >>= 1) {
            s1 += __shfl_down(s1, off, 16);
            s2 += __shfl_down(s2, off, 16);
        }
        s1 = __shfl(s1, 0, 16);
        s2 = __shfl(s2, 0, 16);
        float mu = s1 * (1.f / 256.f);
        float var = s2 * (1.f / 256.f) - mu * mu;
        float inv = rsqrtf(var + 1e-5f);
        #pragma unroll
        for (int i = 0; i < 16; i++) {
            int k = lr * 16 + i;
            xl[r * LDX + k] = f2h((vals[i] - mu) * inv * h2f(g3[k]) + h2f(b3[k]));
        }
    }
    __syncthreads();
    int wave = tid >> 6, lane = tid & 63;
    int l = lane & 15, quad = lane >> 4;
    half8 afr[8];
    {
        const elt* arow = xl + l * LDX + quad * 8;
        #pragma unroll
        for (int ks = 0; ks < 8; ks++)
            afr[ks] = *reinterpret_cast<const half8*>(arow + ks * 32);
    }
    __syncthreads();
    for (int ct = 0; ct < 16; ct++) {
        int col = wave * 256 + ct * 16 + l;
        const elt* wrow = w1T + (size_t)col * 256 + quad * 8;
        f32x4 acc = {0.f, 0.f, 0.f, 0.f};
        #pragma unroll
        for (int ks = 0; ks < 8; ks++) {
            half8 bfr = *reinterpret_cast<const half8*>(wrow + ks * 32);
            acc = mfma16(afr[ks], bfr, acc);
        }
        float bb = h2f(b1[col]);
        #pragma unroll
        for (int r = 0; r < 4; r++)
            hbuf[(quad * 4 + r) * LDH + col] = f2h(fmaxf(acc[r] + bb, 0.f));
    }
    __syncthreads();
    int fdt = flags[0];
    for (int ct = 0; ct < 4; ct++) {
        int col = wave * 64 + ct * 16 + l;
        const elt* wrow = w2T + (size_t)col * 1024 + quad * 8;
        const elt* hrow = hbuf + l * LDH + quad * 8;
        f32x4 acc = {0.f, 0.f, 0.f, 0.f};
        #pragma unroll 8
        for (int ks = 0; ks < 32; ks++) {
            half8 a2 = *reinterpret_cast<const half8*>(hrow + ks * 32);
            half8 bfr = *reinterpret_cast<const half8*>(wrow + ks * 32);
            acc = mfma16(a2, bfr, acc);
        }
        float bb = h2f(b2v[col]);
        #pragma unroll
        for (int r = 0; r < 4; r++) {
            long o = (long)(row0 + quad * 4 + r) * 256 + col;
            store_any(out, o, fdt, x[o] + acc[r] + bb);
        }
    }
}

// ---------------- Temporal sampling: branchless 4-corner, 4 loads in flight ----------------
__global__ __launch_bounds__(256) void temporal_kernel(const elt* __restrict__ ai,
                                                       const elt* __restrict__ toffB,
                                                       const elt* __restrict__ twlB,
                                                       const void* __restrict__ ref2d,
                                                       const void* __restrict__ ego,
                                                       const int* __restrict__ flags,
                                                       elt* __restrict__ tfB) {
    int tid = threadIdx.x;
    int ql = tid >> 5, t = tid & 31;
    int g = t >> 2, q4 = t & 3;
    long n0 = (long)blockIdx.x * 8;
    __shared__ float s_toff[8][8][17];
    __shared__ float s_twl[8][64];
    __shared__ float s_base[8][4];
    for (int i = tid; i < 8 * 128; i += 256) {
        int q = i >> 7, j = i & 127;
        int si = j >> 6, r = j & 63, gg = r >> 3, w = r & 7;
        s_toff[q][gg][si * 8 + w] = h2f(toffB[n0 * 128 + i]);
    }
    for (int i = tid; i < 8 * 64; i += 256) s_twl[i >> 6][i & 63] = h2f(twlB[n0 * 64 + i]);
    if (tid < 8) {
        int f = flags[0];
        float rx = load_any(ref2d, (n0 + tid) * 2, f), ry = load_any(ref2d, (n0 + tid) * 2 + 1, f);
        s_base[tid][0] = rx + load_any(ego, 0, f); s_base[tid][1] = ry + load_any(ego, 1, f);
        s_base[tid][2] = rx;                       s_base[tid][3] = ry;
    }
    __syncthreads();
    float acc[8];
    #pragma unroll
    for (int i = 0; i < 8; i++) acc[i] = 0.f;
    int choff = g * 32 + q4 * 8;
    #pragma unroll
    for (int si = 0; si < 2; si++) {
        float l0 = s_twl[ql][si * 32 + g * 4 + 0], l1 = s_twl[ql][si * 32 + g * 4 + 1];
        float l2 = s_twl[ql][si * 32 + g * 4 + 2], l3 = s_twl[ql][si * 32 + g * 4 + 3];
        float mx = fmaxf(fmaxf(l0, l1), fmaxf(l2, l3));
        float e0 = __expf(l0 - mx), e1 = __expf(l1 - mx);
        float e2 = __expf(l2 - mx), e3 = __expf(l3 - mx);
        float inv = 1.f / (e0 + e1 + e2 + e3);
        float wts[4] = {e0 * inv, e1 * inv, e2 * inv, e3 * inv};
        int aoff = si * 256;
        float bx = s_base[ql][si * 2], by = s_base[ql][si * 2 + 1];
        __half2 hz = __floats2half2_rn(0.f, 0.f);
        __half2 hacc[4] = {hz, hz, hz, hz};
        #pragma unroll
        for (int pt = 0; pt < 4; pt++) {
            float u = bx + s_toff[ql][g][si * 8 + pt * 2 + 0];
            float v = by + s_toff[ql][g][si * 8 + pt * 2 + 1];
            float ix = u * (float)BW - 0.5f;
            float iy = v * (float)BH - 0.5f;
            float x0f = floorf(ix), y0f = floorf(iy);
            int x0 = (int)x0f, y0 = (int)y0f;
            float wx1 = ix - x0f, wy1 = iy - y0f;
            // branchless corners: clamp address, zero weight when OOB
            float wx0v = ((unsigned)x0 < BW) ? (1.f - wx1) : 0.f;
            float wx1v = ((unsigned)(x0 + 1) < BW) ? wx1 : 0.f;
            float wy0v = ((unsigned)y0 < BH) ? (1.f - wy1) : 0.f;
            float wy1v = ((unsigned)(y0 + 1) < BH) ? wy1 : 0.f;
            int x0c = min(max(x0, 0), BW - 1);
            int x1c = min(max(x0 + 1, 0), BW - 1);
            int y0c = min(max(y0, 0), BH - 1);
            int y1c = min(max(y0 + 1, 0), BH - 1);
            const elt* r0 = ai + (long)(y0c * BW) * 512 + aoff + choff;
            const elt* r1 = ai + (long)(y1c * BW) * 512 + aoff + choff;
            uint4 u00 = *reinterpret_cast<const uint4*>(r0 + (long)x0c * 512);
            uint4 u01 = *reinterpret_cast<const uint4*>(r0 + (long)x1c * 512);
            uint4 u10 = *reinterpret_cast<const uint4*>(r1 + (long)x0c * 512);
            uint4 u11 = *reinterpret_cast<const uint4*>(r1 + (long)x1c * 512);
            float wp = wts[pt];
            pkfma8(hacc, __float2half2_rn(wp * wy0v * wx0v), u00);
            pkfma8(hacc, __float2half2_rn(wp * wy0v * wx1v), u01);
            pkfma8(hacc, __float2half2_rn(wp * wy1v * wx0v), u10);
            pkfma8(hacc, __float2half2_rn(wp * wy1v * wx1v), u11);
        }
        // per-direction f32 rollup (bounds the f16 chain to <=16 pk-fmas)
        acc[0] += __low2float(hacc[0]); acc[1] += __high2float(hacc[0]);
        acc[2] += __low2float(hacc[1]); acc[3] += __high2float(hacc[1]);
        acc[4] += __low2float(hacc[2]); acc[5] += __high2float(hacc[2]);
        acc[6] += __low2float(hacc[3]); acc[7] += __high2float(hacc[3]);
    }
    uint4 o;
    o.x = pack2(acc[0] * 0.5f, acc[1] * 0.5f);
    o.y = pack2(acc[2] * 0.5f, acc[3] * 0.5f);
    o.z = pack2(acc[4] * 0.5f, acc[5] * 0.5f);
    o.w = pack2(acc[6] * 0.5f, acc[7] * 0.5f);
    *reinterpret_cast<uint4*>(tfB + (n0 + ql) * 256 + choff) = o;
}

// ---------------- Spatial v15: 2 queries/wave interleaved (8 q/block, grid 1250) ----------------
// Fixes the 1.22-round scheduling tail (10000 waves vs 8192 slots) and doubles per-wave
// memory-level parallelism: per sample, 4 independent loads (2 per query) in flight.
// Per-query math identical to v14 (branchless y, half-wave corner-x, pk-fma f16 accum).
__global__ __launch_bounds__(256) void spatial_kernel(const elt* __restrict__ soffB,
                                                      const elt* __restrict__ swlB,
                                                      const void* __restrict__ refcam,
                                                      const void* __restrict__ bmask,
                                                      const elt* __restrict__ imgT,
                                                      const void* __restrict__ img_raw,
                                                      int use_imgT,
                                                      const int* __restrict__ flags,
                                                      elt* __restrict__ sfB) {
    int tid = threadIdx.x;
    int wave = tid >> 6, lane = tid & 63;
    int qA = wave * 2, qB = qA + 1;
    int cxh = lane >> 5;
    int h5 = lane & 31;
    int g = h5 >> 2, c8 = h5 & 3;
    long n0 = (long)blockIdx.x * 8;
    __shared__ float s_soff[8][8][33];
    __shared__ float s_swl[8][144];        // [q][j*9 + g]
    __shared__ float s_ref[8][NC][PP][2];
    __shared__ int   s_vis[8][NC][PP];
    for (int i = tid; i < 8 * 256; i += 256) {
        int q = i >> 8, j = i & 255;
        s_soff[q][j >> 5][j & 31] = h2f(soffB[n0 * 256 + i]);
    }
    for (int i = tid; i < 8 * 128; i += 256) {
        int q = i >> 7, jr = i & 127;
        int gg = jr >> 4, j = jr & 15;
        s_swl[q][j * 9 + gg] = h2f(swlB[n0 * 128 + i]);
    }
    int fdt = flags[0], msz = flags[1];
    for (int i = tid; i < 8 * 48; i += 256) {
        int q = i / 48, r = i % 48;
        s_ref[q][r >> 3][(r & 7) >> 1][r & 1] =
            load_any(refcam, ((long)(r >> 3) * N_Q + n0 + q) * 8 + (r & 7), fdt);
    }
    for (int i = tid; i < 8 * 24; i += 256) {
        int q = i / 24, r = i % 24; int c = r >> 2, p = r & 3;
        long idx = ((long)c * N_Q + n0 + q) * 4 + p;
        int v;
        if (msz == 1)      v = ((const unsigned char*)bmask)[idx] != 0;
        else if (msz == 2) v = ((const unsigned short*)bmask)[idx] != 0;
        else if (msz == 4) v = ((const unsigned int*)bmask)[idx] != 0u;
        else               v = ((const unsigned long long*)bmask)[idx] != 0ULL;
        s_vis[q][c][p] = v;
    }
    __syncthreads();
    // hoisted softmax numerators for both queries (shift-invariant masked softmax)
    float ewA[16], ewB[16];
    {
        float mxA = -3e38f, mxB = -3e38f;
        #pragma unroll
        for (int j = 0; j < 16; j++) {
            ewA[j] = s_swl[qA][j * 9 + g]; mxA = fmaxf(mxA, ewA[j]);
            ewB[j] = s_swl[qB][j * 9 + g]; mxB = fmaxf(mxB, ewB[j]);
        }
        #pragma unroll
        for (int j = 0; j < 16; j++) {
            ewA[j] = __expf(ewA[j] - mxA);
            ewB[j] = __expf(ewB[j] - mxB);
        }
    }
    float accA[8], accB[8];
    #pragma unroll
    for (int i = 0; i < 8; i++) { accA[i] = 0.f; accB[i] = 0.f; }
    float cntA = 0.f, cntB = 0.f;
    int choff = g * 32 + c8 * 8;
    for (int c = 0; c < NC; c++) {
        int anyA = s_vis[qA][c][0] | s_vis[qA][c][1] | s_vis[qA][c][2] | s_vis[qA][c][3];
        int anyB = s_vis[qB][c][0] | s_vis[qB][c][1] | s_vis[qB][c][2] | s_vis[qB][c][3];
        if (!(anyA | anyB)) continue;
        float sumA = 0.f, sumB = 0.f;
        #pragma unroll
        for (int j = 0; j < 16; j++) {
            sumA += s_vis[qA][c][j >> 2] ? ewA[j] : 0.f;
            sumB += s_vis[qB][c][j >> 2] ? ewB[j] : 0.f;
        }
        float invA = anyA ? 1.f / fmaxf(sumA, 1e-20f) : 0.f;
        float invB = anyB ? 1.f / fmaxf(sumB, 1e-20f) : 0.f;
        cntA += anyA ? 1.f : 0.f;
        cntB += anyB ? 1.f : 0.f;
        const elt* img = imgT + (long)c * HF * WF * 256 + choff;
        __half2 hz = __floats2half2_rn(0.f, 0.f);
        __half2 haA[4] = {hz, hz, hz, hz}, haB[4] = {hz, hz, hz, hz};
        #pragma unroll
        for (int p = 0; p < PP; p++) {
            int vpA = s_vis[qA][c][p], vpB = s_vis[qB][c][p];
            if (!(vpA | vpB)) continue;
            float wfA = vpA ? invA : 0.f;      // zero-weight path for the invisible query
            float wfB = vpB ? invB : 0.f;
            float rxA = s_ref[qA][c][p][0], ryA = s_ref[qA][c][p][1];
            float rxB = s_ref[qB][c][p][0], ryB = s_ref[qB][c][p][1];
            #pragma unroll
            for (int s = 0; s < PS; s++) {
                float wiA = ewA[p * 4 + s] * wfA;
                float wiB = ewB[p * 4 + s] * wfB;
                float uA = rxA + s_soff[qA][g][p * 8 + s * 2 + 0];
                float vA = ryA + s_soff[qA][g][p * 8 + s * 2 + 1];
                float uB = rxB + s_soff[qB][g][p * 8 + s * 2 + 0];
                float vB = ryB + s_soff[qB][g][p * 8 + s * 2 + 1];
                float ixA = uA * (float)WF - 0.5f, iyA = vA * (float)HF - 0.5f;
                float ixB = uB * (float)WF - 0.5f, iyB = vB * (float)HF - 0.5f;
                float xfA = floorf(ixA), yfA = floorf(iyA);
                float xfB = floorf(ixB), yfB = floorf(iyB);
                int x0A = (int)xfA, y0A = (int)yfA;
                int x0B = (int)xfB, y0B = (int)yfB;
                float wx1A = ixA - xfA, wy1A = iyA - yfA;
                float wx1B = ixB - xfB, wy1B = iyB - yfB;
                int xiA = x0A + cxh, xiB = x0B + cxh;
                float wxA = cxh ? wx1A : (1.f - wx1A);
                float wxB = cxh ? wx1B : (1.f - wx1B);
                wxA = ((unsigned)xiA < WF) ? wxA : 0.f;
                wxB = ((unsigned)xiB < WF) ? wxB : 0.f;
                int xcA = min(max(xiA, 0), WF - 1);
                int xcB = min(max(xiB, 0), WF - 1);
                float wwA = wiA * wxA, wwB = wiB * wxB;
                float wy0A = ((unsigned)y0A < HF) ? (1.f - wy1A) : 0.f;
                float wy1vA = ((unsigned)(y0A + 1) < HF) ? wy1A : 0.f;
                float wy0B = ((unsigned)y0B < HF) ? (1.f - wy1B) : 0.f;
                float wy1vB = ((unsigned)(y0B + 1) < HF) ? wy1B : 0.f;
                int ya0 = min(max(y0A, 0), HF - 1), ya1 = min(max(y0A + 1, 0), HF - 1);
                int yb0 = min(max(y0B, 0), HF - 1), yb1 = min(max(y0B + 1, 0), HF - 1);
                if (use_imgT) {
                    // 4 independent loads in flight before any dependent fma
                    uint4 a0 = *reinterpret_cast<const uint4*>(img + (long)(ya0 * WF + xcA) * 256);
                    uint4 a1 = *reinterpret_cast<const uint4*>(img + (long)(ya1 * WF + xcA) * 256);
                    uint4 b0 = *reinterpret_cast<const uint4*>(img + (long)(yb0 * WF + xcB) * 256);
                    uint4 b1 = *reinterpret_cast<const uint4*>(img + (long)(yb1 * WF + xcB) * 256);
                    pkfma8(haA, __float2half2_rn(wwA * wy0A), a0);
                    pkfma8(haA, __float2half2_rn(wwA * wy1vA), a1);
                    pkfma8(haB, __float2half2_rn(wwB * wy0B), b0);
                    pkfma8(haB, __float2half2_rn(wwB * wy1vB), b1);
                } else {
                    #pragma unroll
                    for (int e = 0; e < 8; e++) {
                        long base = ((long)c * 256 + choff + e) * HF;
                        accA[e] += (wwA * wy0A) * load_any(img_raw, (base + ya0) * WF + xcA, fdt)
                                 + (wwA * wy1vA) * load_any(img_raw, (base + ya1) * WF + xcA, fdt);
                        accB[e] += (wwB * wy0B) * load_any(img_raw, (base + yb0) * WF + xcB, fdt)
                                 + (wwB * wy1vB) * load_any(img_raw, (base + yb1) * WF + xcB, fdt);
                    }
                }
            }
        }
        // per-camera f32 rollup (bounds the f16 chain to <=32 pk-fmas)
        accA[0] += __low2float(haA[0]); accA[1] += __high2float(haA[0]);
        accA[2] += __low2float(haA[1]); accA[3] += __high2float(haA[1]);
        accA[4] += __low2float(haA[2]); accA[5] += __high2float(haA[2]);
        accA[6] += __low2float(haA[3]); accA[7] += __high2float(haA[3]);
        accB[0] += __low2float(haB[0]); accB[1] += __high2float(haB[0]);
        accB[2] += __low2float(haB[1]); accB[3] += __high2float(haB[1]);
        accB[4] += __low2float(haB[2]); accB[5] += __high2float(haB[2]);
        accB[6] += __low2float(haB[3]); accB[7] += __high2float(haB[3]);
    }
    // combine the two corner-x halves: lane i and lane i^32 hold same channels
    #pragma unroll
    for (int e = 0; e < 8; e++) {
        accA[e] += __shfl_xor(accA[e], 32);
        accB[e] += __shfl_xor(accB[e], 32);
    }
    if (cxh == 0) {
        float ivA = 1.f / fmaxf(cntA, 1.f);
        uint4 oA;
        oA.x = pack2(accA[0] * ivA, accA[1] * ivA);
        oA.y = pack2(accA[2] * ivA, accA[3] * ivA);
        oA.z = pack2(accA[4] * ivA, accA[5] * ivA);
        oA.w = pack2(accA[6] * ivA, accA[7] * ivA);
        *reinterpret_cast<uint4*>(sfB + (n0 + qA) * 256 + choff) = oA;
        float ivB = 1.f / fmaxf(cntB, 1.f);
        uint4 oB;
        oB.x = pack2(accB[0] * ivB, accB[1] * ivB);
        oB.y = pack2(accB[2] * ivB, accB[3] * ivB);
        oB.z = pack2(accB[4] * ivB, accB[5] * ivB);
        oB.w = pack2(accB[6] * ivB, accB[7] * ivB);
        *reinterpret_cast<uint4*>(sfB + (n0 + qB) * 256 + choff) = oB;
    }
}

// f16 element offsets inside the weight region (matrices stored TRANSPOSED [J][K])
#define W_TOFF_W 0
#define W_TOFF_B 65536
#define W_TWT_W  65664
#define W_TWT_B  98432
#define W_TOUT_W 98496
#define W_TOUT_B 164032
#define W_SOFF_W 164288
#define W_SOFF_B 229824
#define W_SWT_W  230080
#define W_SWT_B  262848
#define W_SOUT_W 262976
#define W_SOUT_B 328512
#define W_FFN_W1 328768
#define W_FFN_B1 590912
#define W_FFN_W2 591936
#define W_FFN_B2 854080
#define W_LN1_G  854336
#define W_LN1_B  854592
#define W_LN2_G  854848
#define W_LN2_B  855104
#define W_LN3_G  855360
#define W_LN3_B  855616

// byte offsets in workspace (total ~35.6 MB)
#define OB_WGT   0
#define OB_FLAGS 1711744
#define OB_AI    1712640
#define OB_TF    11952640
#define OB_X     17072640
#define OB_T4    27312640
#define OB_IMG   31152640
#define WS_NEED_IMG 35576320ULL

extern "C" void kernel_launch(void* const* d_in, const int* in_sizes, int n_in,
                              void* d_out, int out_size, void* d_ws, size_t ws_size,
                              hipStream_t stream) {
    char* W8 = (char*)d_ws;
    elt*   wgt   = (elt*)(W8 + OB_WGT);
    int*   flags = (int*)(W8 + OB_FLAGS);
    elt*   ai    = (elt*)(W8 + OB_AI);                  // N x 512, pb | q1
    elt*   q2B   = ai;                                  // N x 256 (after temporal)
    elt*   sfB   = (elt*)(W8 + OB_AI + 5120000);        // N x 256
    elt*   tfB   = (elt*)(W8 + OB_TF);                  // N x 256
    elt*   soffB = tfB;                                 // N x 256 (after t_out gemm)
    float* x     = (float*)(W8 + OB_X);                 // N x 256 f32 trunk
    elt*   toffB = (elt*)(W8 + OB_T4);                  // N x 128
    elt*   twlB  = (elt*)(W8 + OB_T4 + 2560000);        // N x 64
    elt*   swlB  = toffB;                               // N x 128 (after temporal)
    elt*   imgT  = (elt*)(W8 + OB_IMG);                 // NC*HF*WF*256
    int use_imgT = (ws_size >= WS_NEED_IMG) ? 1 : 0;

    detect_kernel<<<1, 256, 0, stream>>>(d_in[22], d_in[28], flags);

    {   // unified prep: 8 transposes + 14 flat cvts + img transpose
        PrepDesc pd;
        const int tsrc[8] = {6, 8, 10, 12, 14, 16, 18, 20};
        const int toff[8] = {W_TOFF_W, W_TWT_W, W_TOUT_W, W_SOFF_W, W_SWT_W, W_SOUT_W,
                             W_FFN_W1, W_FFN_W2};
        const int tR[8] = {512, 512, 256, 256, 256, 256, 256, 1024};
        const int tC[8] = {128, 64, 256, 256, 128, 256, 1024, 256};
        const int fsrc[14] = {7, 9, 11, 13, 15, 17, 19, 21, 22, 23, 24, 25, 26, 27};
        const int foff[14] = {W_TOFF_B, W_TWT_B, W_TOUT_B, W_SOFF_B, W_SWT_B, W_SOUT_B,
                              W_FFN_B1, W_FFN_B2, W_LN1_G, W_LN1_B, W_LN2_G, W_LN2_B,
                              W_LN3_G, W_LN3_B};
        const int fcnt[14] = {128, 64, 256, 256, 128, 256, 1024, 256, 256, 256, 256, 256, 256, 256};
        int a = 0, blk = 0;
        for (int i = 0; i < 8; i++, a++) {
            pd.src[a] = d_in[tsrc[i]]; pd.dst_off[a] = toff[i];
            pd.count[a] = tR[i] * tC[i]; pd.R[a] = tR[i]; pd.C[a] = tC[i];
            pd.type[a] = 1; pd.blk_start[a] = blk; blk += (pd.count[a] + 255) / 256;
        }
        for (int i = 0; i < 14; i++, a++) {
            pd.src[a] = d_in[fsrc[i]]; pd.dst_off[a] = foff[i];
            pd.count[a] = fcnt[i]; pd.R[a] = 0; pd.C[a] = 0;
            pd.type[a] = 0; pd.blk_start[a] = blk; blk += (pd.count[a] + 255) / 256;
        }
        pd.src[a] = d_in[2]; pd.dst_off[a] = 0;
        pd.count[a] = use_imgT ? NC * HF * WF * 256 : 0;
        pd.R[a] = 0; pd.C[a] = 0; pd.type[a] = 2; pd.blk_start[a] = blk;
        blk += (pd.count[a] + 255) / 256;
        pd.blk_start[NP] = blk;
        prep_kernel<<<blk, 256, 0, stream>>>(pd, wgt, imgT, flags);
    }

    ln12_kernel<<<5000, 256, 0, stream>>>(d_in[1], d_in[0], flags,
                                          wgt + W_LN1_G, wgt + W_LN1_B, ai);
    gemm_dual<512, 128, 64><<<dim3(313, 3), 256, 0, stream>>>(ai,
        wgt + W_TOFF_W, wgt + W_TOFF_B, T_RAD, toffB,
        wgt + W_TWT_W, wgt + W_TWT_B, twlB);
    temporal_kernel<<<1250, 256, 0, stream>>>(ai, toffB, twlB, d_in[3], d_in[5], flags, tfB);
    gemm_mfma<256, 256, 2><<<dim3(313, 4), 256, 0, stream>>>(tfB, wgt + W_TOUT_W, wgt + W_TOUT_B,
        x, d_in[0], nullptr, flags);
    ln_kernel<<<2500, 256, 0, stream>>>(x, wgt + W_LN2_G, wgt + W_LN2_B, q2B);
    gemm_dual<256, 256, 128><<<dim3(313, 6), 256, 0, stream>>>(q2B,
        wgt + W_SOFF_W, wgt + W_SOFF_B, S_RAD, soffB,
        wgt + W_SWT_W, wgt + W_SWT_B, swlB);
    spatial_kernel<<<1250, 256, 0, stream>>>(soffB, swlB, d_in[4], d_in[28], imgT, d_in[2],
                                             use_imgT, flags, sfB);
    gemm_mfma<256, 256, 3><<<dim3(313, 4), 256, 0, stream>>>(sfB, wgt + W_SOUT_W, wgt + W_SOUT_B,
        x, nullptr, x, flags);
    ffn_mfma<<<625, 256, 0, stream>>>(x, wgt + W_LN3_G, wgt + W_LN3_B,
                                      wgt + W_FFN_W1, wgt + W_FFN_B1,
                                      wgt + W_FFN_W2, wgt + W_FFN_B2, d_out, flags);
}

// Round 10
// 442.885 us; speedup vs baseline: 1.0783x; 1.0783x over previous
//
#include <hip/hip_runtime.h>
#include <hip/hip_bf16.h>
#include <hip/hip_fp16.h>

#define N_Q 10000
#define D_MODEL 256
#define NH 8
#define PT 4
#define PP 4
#define PS 4
#define DFF 1024
#define NC 6
#define HF 24
#define WF 60
#define BH 100
#define BW 100
#define T_RAD 0.15f
#define S_RAD 0.12f

typedef __hip_bfloat16 bf16;
typedef __half elt;                 // internal storage type: f16 (enables v_pk_fma_f16)
typedef _Float16 __attribute__((ext_vector_type(8))) half8;
typedef __attribute__((ext_vector_type(4))) float f32x4;

__device__ __forceinline__ float h2f(elt v) { return __half2float(v); }
__device__ __forceinline__ elt f2h(float v) { return __float2half(v); }

__device__ __forceinline__ f32x4 mfma16(half8 a, half8 b, f32x4 c) {
    return __builtin_amdgcn_mfma_f32_16x16x32_f16(a, b, c, 0, 0, 0);
}

// dtype-adaptive loads/stores for INPUT tensors; f: 0=f32, 1=bf16, 2=f16
__device__ __forceinline__ float load_any(const void* p, long i, int f) {
    if (f == 0) return ((const float*)p)[i];
    if (f == 1) return __bfloat162float(((const bf16*)p)[i]);
    return __half2float(((const __half*)p)[i]);
}
__device__ __forceinline__ void store_any(void* p, long i, int f, float v) {
    if (f == 0)      ((float*)p)[i] = v;
    else if (f == 1) ((bf16*)p)[i] = __float2bfloat16(v);
    else             ((__half*)p)[i] = __float2half(v);
}

__device__ __forceinline__ unsigned pack2(float a, float b) {
    __half2 h = __floats2half2_rn(a, b);
    return *(unsigned*)&h;
}

// 8-channel packed-f16 accumulate from one uint4: 4 x v_pk_fma_f16
__device__ __forceinline__ void pkfma8(__half2* hacc, __half2 w2, uint4 uu) {
    hacc[0] = __hfma2(*(__half2*)&uu.x, w2, hacc[0]);
    hacc[1] = __hfma2(*(__half2*)&uu.y, w2, hacc[1]);
    hacc[2] = __hfma2(*(__half2*)&uu.z, w2, hacc[2]);
    hacc[3] = __hfma2(*(__half2*)&uu.w, w2, hacc[3]);
}

// ---------------- dtype / mask-width detection (parallel) ----------------
__global__ __launch_bounds__(256) void detect_kernel(const void* __restrict__ ln1g,
                                                     const void* __restrict__ mask,
                                                     int* __restrict__ flags) {
    __shared__ int sh[6];
    int tid = threadIdx.x;
    if (tid < 6) sh[tid] = (tid == 0 || tid == 2 || tid == 4) ? 1 : 0;
    __syncthreads();
    const unsigned long long* m64 = (const unsigned long long*)mask;
    const unsigned int*       m32 = (const unsigned int*)mask;
    const unsigned short*     m16 = (const unsigned short*)mask;
    int lok8 = 1, lones8 = 0, lok4 = 1, lones4 = 0, lok2 = 1, lones2 = 0;
    for (int i = tid; i < 480; i += 256) {
        if (i < 120) {
            unsigned long long v = m64[i];
            if (v == 1ULL) lones8++; else if (v != 0ULL) lok8 = 0;
        }
        if (i < 240) {
            unsigned int v = m32[i];
            if (v == 1u || v == 0x3F800000u) lones4++; else if (v != 0u) lok4 = 0;
        }
        unsigned short v = m16[i];
        if (v == 1 || v == 0x3F80) lones2++; else if (v != 0) lok2 = 0;
    }
    atomicAnd(&sh[0], lok8); atomicAdd(&sh[1], lones8);
    atomicAnd(&sh[2], lok4); atomicAdd(&sh[3], lones4);
    atomicAnd(&sh[4], lok2); atomicAdd(&sh[5], lones2);
    __syncthreads();
    if (tid == 0) {
        unsigned short u0 = ((const unsigned short*)ln1g)[0];
        flags[0] = (u0 == 0x3F80) ? 1 : (u0 == 0x3C00 ? 2 : 0);
        int ms;
        if (sh[0] && sh[1] > 30)       ms = 8;
        else if (sh[2] && sh[3] > 60)  ms = 4;
        else if (sh[4] && sh[5] > 120) ms = 2;
        else                           ms = 1;
        flags[1] = ms;
    }
}

// ---------------- unified weight/image prep: transposes + flat cvt + img transpose ----------------
#define NP 23
struct PrepDesc {
    const void* src[NP];
    int dst_off[NP];
    int count[NP];
    int R[NP];
    int C[NP];
    int type[NP];       // 0 flat cvt, 1 transpose, 2 img transpose
    int blk_start[NP + 1];
};
__global__ __launch_bounds__(256) void prep_kernel(PrepDesc pd, elt* __restrict__ wgt,
                                                   elt* __restrict__ imgT,
                                                   const int* __restrict__ flags) {
    int blk = blockIdx.x;
    int a = 0;
    while (a < NP - 1 && blk >= pd.blk_start[a + 1]) a++;
    int i = (blk - pd.blk_start[a]) * 256 + threadIdx.x;
    if (i >= pd.count[a]) return;
    int f = flags[0];
    int ty = pd.type[a];
    if (ty == 0) {
        wgt[pd.dst_off[a] + i] = f2h(load_any(pd.src[a], i, f));
    } else if (ty == 1) {
        int R = pd.R[a], C = pd.C[a];
        int c = i / R, r = i % R;
        wgt[pd.dst_off[a] + i] = f2h(load_any(pd.src[a], (long)r * C + c, f));
    } else {
        int ch = i & 255;
        int t = i >> 8;
        int xx = t % WF; t /= WF;
        int yy = t % HF;
        int c  = t / HF;
        long src = (((long)(c * 256) + ch) * HF + yy) * WF + xx;
        imgT[i] = f2h(load_any(pd.src[a], src, f));
    }
}

// ---------------- LN1 over prev_bev & query, wave-per-row -> ai[N,512] ----------------
__global__ __launch_bounds__(256) void ln12_kernel(const void* __restrict__ pb,
                                                   const void* __restrict__ q,
                                                   const int* __restrict__ flags,
                                                   const elt* __restrict__ g,
                                                   const elt* __restrict__ b,
                                                   elt* __restrict__ out) {
    int wv = threadIdx.x >> 6, lane = threadIdx.x & 63;
    long row = (long)blockIdx.x * 4 + wv;
    const void* src; long r; int ooff;
    if (row < N_Q) { src = pb; r = row; ooff = 0; }
    else           { src = q;  r = row - N_Q; ooff = 256; }
    int f = flags[0];
    float v0, v1, v2, v3;
    if (f == 0) {
        float4 t = ((const float4*)src)[r * 64 + lane];
        v0 = t.x; v1 = t.y; v2 = t.z; v3 = t.w;
    } else {
        uint2 t = ((const uint2*)src)[r * 64 + lane];
        if (f == 1) {
            v0 = __uint_as_float(t.x << 16); v1 = __uint_as_float(t.x & 0xFFFF0000u);
            v2 = __uint_as_float(t.y << 16); v3 = __uint_as_float(t.y & 0xFFFF0000u);
        } else {
            __half2 h0 = *(__half2*)&t.x, h1 = *(__half2*)&t.y;
            v0 = __half2float(h0.x); v1 = __half2float(h0.y);
            v2 = __half2float(h1.x); v3 = __half2float(h1.y);
        }
    }
    float s1 = v0 + v1 + v2 + v3;
    float s2 = v0 * v0 + v1 * v1 + v2 * v2 + v3 * v3;
    #pragma unroll
    for (int m = 32; m > 0; m >>= 1) {
        s1 += __shfl_xor(s1, m);
        s2 += __shfl_xor(s2, m);
    }
    float mu = s1 * (1.f / 256.f);
    float var = s2 * (1.f / 256.f) - mu * mu;
    float inv = rsqrtf(var + 1e-5f);
    int k = lane * 4;
    float o0 = (v0 - mu) * inv * h2f(g[k+0]) + h2f(b[k+0]);
    float o1 = (v1 - mu) * inv * h2f(g[k+1]) + h2f(b[k+1]);
    float o2 = (v2 - mu) * inv * h2f(g[k+2]) + h2f(b[k+2]);
    float o3 = (v3 - mu) * inv * h2f(g[k+3]) + h2f(b[k+3]);
    uint2 st = {pack2(o0, o1), pack2(o2, o3)};
    *reinterpret_cast<uint2*>(out + r * 512 + ooff + k) = st;
}

// ---------------- LayerNorm (f32 in), wave-per-row -> f16 out ----------------
__global__ __launch_bounds__(256) void ln_kernel(const float* __restrict__ in,
                                                 const elt* __restrict__ g,
                                                 const elt* __restrict__ b,
                                                 elt* __restrict__ out) {
    int wv = threadIdx.x >> 6, lane = threadIdx.x & 63;
    long r = (long)blockIdx.x * 4 + wv;
    float4 t = ((const float4*)in)[r * 64 + lane];
    float s1 = t.x + t.y + t.z + t.w;
    float s2 = t.x * t.x + t.y * t.y + t.z * t.z + t.w * t.w;
    #pragma unroll
    for (int m = 32; m > 0; m >>= 1) {
        s1 += __shfl_xor(s1, m);
        s2 += __shfl_xor(s2, m);
    }
    float mu = s1 * (1.f / 256.f);
    float var = s2 * (1.f / 256.f) - mu * mu;
    float inv = rsqrtf(var + 1e-5f);
    int k = lane * 4;
    float o0 = (t.x - mu) * inv * h2f(g[k+0]) + h2f(b[k+0]);
    float o1 = (t.y - mu) * inv * h2f(g[k+1]) + h2f(b[k+1]);
    float o2 = (t.z - mu) * inv * h2f(g[k+2]) + h2f(b[k+2]);
    float o3 = (t.w - mu) * inv * h2f(g[k+3]) + h2f(b[k+3]);
    uint2 st = {pack2(o0, o1), pack2(o2, o3)};
    *reinterpret_cast<uint2*>(out + r * 256 + k) = st;
}

// ---------------- MFMA GEMM: out[M,J] = A @ WT^T + bias; cols split by blockIdx.y ----------------
template <int K, int J, int MODE>
__global__ __launch_bounds__(256) void gemm_mfma(const elt* __restrict__ A,
                                                 const elt* __restrict__ WT,
                                                 const elt* __restrict__ bias,
                                                 float* __restrict__ outf,
                                                 const void* __restrict__ resraw,
                                                 const float* __restrict__ resf,
                                                 const int* __restrict__ flags) {
    constexpr int LDK = K + 8;
    __shared__ elt As[32 * LDK];
    int tid = threadIdx.x;
    int row0 = blockIdx.x * 32;
    int col0 = blockIdx.y * 64;
    for (int t = tid; t < 32 * (K / 8); t += 256) {
        int r = t / (K / 8), kq = t % (K / 8);
        uint4 u = {0u, 0u, 0u, 0u};
        if (row0 + r < N_Q)
            u = *reinterpret_cast<const uint4*>(A + (size_t)(row0 + r) * K + kq * 8);
        *reinterpret_cast<uint4*>(&As[r * LDK + kq * 8]) = u;
    }
    __syncthreads();
    int wave = tid >> 6, lane = tid & 63;
    int l = lane & 15, quad = lane >> 4;
    int rh = wave >> 1, ch = wave & 1;
    constexpr int NK = K / 32;
    half8 afr[NK];
    const elt* arow = &As[(rh * 16 + l) * LDK + quad * 8];
    #pragma unroll
    for (int ks = 0; ks < NK; ks++)
        afr[ks] = *reinterpret_cast<const half8*>(arow + ks * 32);
    int fdt = flags[0];
    #pragma unroll
    for (int ct = 0; ct < 2; ct++) {
        int col = col0 + ch * 32 + ct * 16 + l;
        const elt* wrow = WT + (size_t)col * K + quad * 8;
        f32x4 acc = {0.f, 0.f, 0.f, 0.f};
        #pragma unroll
        for (int ks = 0; ks < NK; ks++) {
            half8 bfr = *reinterpret_cast<const half8*>(wrow + ks * 32);
            acc = mfma16(afr[ks], bfr, acc);
        }
        float bb = h2f(bias[col]);
        #pragma unroll
        for (int r = 0; r < 4; r++) {
            int row = row0 + rh * 16 + quad * 4 + r;
            if (row >= N_Q) continue;
            long o = (long)row * J + col;
            float v = acc[r] + bb;
            if (MODE == 2) outf[o] = v + load_any(resraw, o, fdt);
            else           outf[o] = v + resf[o];
        }
    }
}

// ---------------- Dual MFMA GEMM (concat cols J1|J2); out1=tanh*scale f16, out2 plain f16 ----
template <int K, int J1, int J2>
__global__ __launch_bounds__(256) void gemm_dual(const elt* __restrict__ A,
                                                 const elt* __restrict__ WT1,
                                                 const elt* __restrict__ b1, float scale,
                                                 elt* __restrict__ out1,
                                                 const elt* __restrict__ WT2,
                                                 const elt* __restrict__ b2,
                                                 elt* __restrict__ out2) {
    constexpr int LDK = K + 8;
    __shared__ elt As[32 * LDK];
    int tid = threadIdx.x;
    int row0 = blockIdx.x * 32;
    int col0 = blockIdx.y * 64;
    for (int t = tid; t < 32 * (K / 8); t += 256) {
        int r = t / (K / 8), kq = t % (K / 8);
        uint4 u = {0u, 0u, 0u, 0u};
        if (row0 + r < N_Q)
            u = *reinterpret_cast<const uint4*>(A + (size_t)(row0 + r) * K + kq * 8);
        *reinterpret_cast<uint4*>(&As[r * LDK + kq * 8]) = u;
    }
    __syncthreads();
    int wave = tid >> 6, lane = tid & 63;
    int l = lane & 15, quad = lane >> 4;
    int rh = wave >> 1, ch = wave & 1;
    constexpr int NK = K / 32;
    half8 afr[NK];
    const elt* arow = &As[(rh * 16 + l) * LDK + quad * 8];
    #pragma unroll
    for (int ks = 0; ks < NK; ks++)
        afr[ks] = *reinterpret_cast<const half8*>(arow + ks * 32);
    #pragma unroll
    for (int ct = 0; ct < 2; ct++) {
        int jg = col0 + ch * 32 + ct * 16 + l;
        int in1 = jg < J1;
        int cl = in1 ? jg : jg - J1;
        const elt* wrow = (in1 ? WT1 : WT2) + (size_t)cl * K + quad * 8;
        f32x4 acc = {0.f, 0.f, 0.f, 0.f};
        #pragma unroll
        for (int ks = 0; ks < NK; ks++) {
            half8 bfr = *reinterpret_cast<const half8*>(wrow + ks * 32);
            acc = mfma16(afr[ks], bfr, acc);
        }
        float bb = h2f(in1 ? b1[cl] : b2[cl]);
        #pragma unroll
        for (int r = 0; r < 4; r++) {
            int row = row0 + rh * 16 + quad * 4 + r;
            if (row >= N_Q) continue;
            float v = acc[r] + bb;
            if (in1) out1[(long)row * J1 + cl] = f2h(tanhf(v) * scale);
            else     out2[(long)row * J2 + cl] = f2h(v);
        }
    }
}

// ---------------- Fused MFMA FFN: LN3 -> @w1T,relu -> @w2T -> +x -> out ----------------
__global__ __launch_bounds__(256) void ffn_mfma(const float* __restrict__ x,
                                                const elt* __restrict__ g3,
                                                const elt* __restrict__ b3,
                                                const elt* __restrict__ w1T,
                                                const elt* __restrict__ b1,
                                                const elt* __restrict__ w2T,
                                                const elt* __restrict__ b2v,
                                                void* __restrict__ out,
                                                const int* __restrict__ flags) {
    constexpr int LDH = DFF + 8;
    constexpr int LDX = D_MODEL + 8;
    __shared__ elt hbuf[16 * LDH];
    elt* xl = hbuf;
    int tid = threadIdx.x;
    int row0 = blockIdx.x * 16;
    {
        int r = tid >> 4, lr = tid & 15;
        const float* xr = x + (long)(row0 + r) * 256 + lr * 16;
        float vals[16];
        float s1 = 0.f, s2 = 0.f;
        #pragma unroll
        for (int i = 0; i < 16; i++) {
            float v = xr[i];
            vals[i] = v; s1 += v; s2 += v * v;
        }
        #pragma unroll
        for (int off = 8; off > 0; off >>= 1) {
            s1 += __shfl_down(s1, off, 16);
            s2 += __shfl_down(s2, off, 16);
        }
        s1 = __shfl(s1, 0, 16);
        s2 = __shfl(s2, 0, 16);
        float mu = s1 * (1.f / 256.f);
        float var = s2 * (1.f / 256.f) - mu * mu;
        float inv = rsqrtf(var + 1e-5f);
        #pragma unroll
        for (int i = 0; i < 16; i++) {
            int k = lr * 16 + i;
            xl[r * LDX + k] = f2h((vals[i] - mu) * inv * h2f(g3[k]) + h2f(b3[k]));
        }
    }
    __syncthreads();
    int wave = tid >> 6, lane = tid & 63;
    int l = lane & 15, quad = lane >> 4;
    half8 afr[8];
    {
        const elt* arow = xl + l * LDX + quad * 8;
        #pragma unroll
        for (int ks = 0; ks < 8; ks++)
            afr[ks] = *reinterpret_cast<const half8*>(arow + ks * 32);
    }
    __syncthreads();
    for (int ct = 0; ct < 16; ct++) {
        int col = wave * 256 + ct * 16 + l;
        const elt* wrow = w1T + (size_t)col * 256 + quad * 8;
        f32x4 acc = {0.f, 0.f, 0.f, 0.f};
        #pragma unroll
        for (int ks = 0; ks < 8; ks++) {
            half8 bfr = *reinterpret_cast<const half8*>(wrow + ks * 32);
            acc = mfma16(afr[ks], bfr, acc);
        }
        float bb = h2f(b1[col]);
        #pragma unroll
        for (int r = 0; r < 4; r++)
            hbuf[(quad * 4 + r) * LDH + col] = f2h(fmaxf(acc[r] + bb, 0.f));
    }
    __syncthreads();
    int fdt = flags[0];
    for (int ct = 0; ct < 4; ct++) {
        int col = wave * 64 + ct * 16 + l;
        const elt* wrow = w2T + (size_t)col * 1024 + quad * 8;
        const elt* hrow = hbuf + l * LDH + quad * 8;
        f32x4 acc = {0.f, 0.f, 0.f, 0.f};
        #pragma unroll 8
        for (int ks = 0; ks < 32; ks++) {
            half8 a2 = *reinterpret_cast<const half8*>(hrow + ks * 32);
            half8 bfr = *reinterpret_cast<const half8*>(wrow + ks * 32);
            acc = mfma16(a2, bfr, acc);
        }
        float bb = h2f(b2v[col]);
        #pragma unroll
        for (int r = 0; r < 4; r++) {
            long o = (long)(row0 + quad * 4 + r) * 256 + col;
            store_any(out, o, fdt, x[o] + acc[r] + bb);
        }
    }
}

// ---------------- Temporal sampling: branchless 4-corner, 4 loads in flight ----------------
__global__ __launch_bounds__(256) void temporal_kernel(const elt* __restrict__ ai,
                                                       const elt* __restrict__ toffB,
                                                       const elt* __restrict__ twlB,
                                                       const void* __restrict__ ref2d,
                                                       const void* __restrict__ ego,
                                                       const int* __restrict__ flags,
                                                       elt* __restrict__ tfB) {
    int tid = threadIdx.x;
    int ql = tid >> 5, t = tid & 31;
    int g = t >> 2, q4 = t & 3;
    long n0 = (long)blockIdx.x * 8;
    __shared__ float s_toff[8][8][17];
    __shared__ float s_twl[8][64];
    __shared__ float s_base[8][4];
    for (int i = tid; i < 8 * 128; i += 256) {
        int q = i >> 7, j = i & 127;
        int si = j >> 6, r = j & 63, gg = r >> 3, w = r & 7;
        s_toff[q][gg][si * 8 + w] = h2f(toffB[n0 * 128 + i]);
    }
    for (int i = tid; i < 8 * 64; i += 256) s_twl[i >> 6][i & 63] = h2f(twlB[n0 * 64 + i]);
    if (tid < 8) {
        int f = flags[0];
        float rx = load_any(ref2d, (n0 + tid) * 2, f), ry = load_any(ref2d, (n0 + tid) * 2 + 1, f);
        s_base[tid][0] = rx + load_any(ego, 0, f); s_base[tid][1] = ry + load_any(ego, 1, f);
        s_base[tid][2] = rx;                       s_base[tid][3] = ry;
    }
    __syncthreads();
    float acc[8];
    #pragma unroll
    for (int i = 0; i < 8; i++) acc[i] = 0.f;
    int choff = g * 32 + q4 * 8;
    #pragma unroll
    for (int si = 0; si < 2; si++) {
        float l0 = s_twl[ql][si * 32 + g * 4 + 0], l1 = s_twl[ql][si * 32 + g * 4 + 1];
        float l2 = s_twl[ql][si * 32 + g * 4 + 2], l3 = s_twl[ql][si * 32 + g * 4 + 3];
        float mx = fmaxf(fmaxf(l0, l1), fmaxf(l2, l3));
        float e0 = __expf(l0 - mx), e1 = __expf(l1 - mx);
        float e2 = __expf(l2 - mx), e3 = __expf(l3 - mx);
        float inv = 1.f / (e0 + e1 + e2 + e3);
        float wts[4] = {e0 * inv, e1 * inv, e2 * inv, e3 * inv};
        int aoff = si * 256;
        float bx = s_base[ql][si * 2], by = s_base[ql][si * 2 + 1];
        __half2 hz = __floats2half2_rn(0.f, 0.f);
        __half2 hacc[4] = {hz, hz, hz, hz};
        #pragma unroll
        for (int pt = 0; pt < 4; pt++) {
            float u = bx + s_toff[ql][g][si * 8 + pt * 2 + 0];
            float v = by + s_toff[ql][g][si * 8 + pt * 2 + 1];
            float ix = u * (float)BW - 0.5f;
            float iy = v * (float)BH - 0.5f;
            float x0f = floorf(ix), y0f = floorf(iy);
            int x0 = (int)x0f, y0 = (int)y0f;
            float wx1 = ix - x0f, wy1 = iy - y0f;
            // branchless corners: clamp address, zero weight when OOB
            float wx0v = ((unsigned)x0 < BW) ? (1.f - wx1) : 0.f;
            float wx1v = ((unsigned)(x0 + 1) < BW) ? wx1 : 0.f;
            float wy0v = ((unsigned)y0 < BH) ? (1.f - wy1) : 0.f;
            float wy1v = ((unsigned)(y0 + 1) < BH) ? wy1 : 0.f;
            int x0c = min(max(x0, 0), BW - 1);
            int x1c = min(max(x0 + 1, 0), BW - 1);
            int y0c = min(max(y0, 0), BH - 1);
            int y1c = min(max(y0 + 1, 0), BH - 1);
            const elt* r0 = ai + (long)(y0c * BW) * 512 + aoff + choff;
            const elt* r1 = ai + (long)(y1c * BW) * 512 + aoff + choff;
            uint4 u00 = *reinterpret_cast<const uint4*>(r0 + (long)x0c * 512);
            uint4 u01 = *reinterpret_cast<const uint4*>(r0 + (long)x1c * 512);
            uint4 u10 = *reinterpret_cast<const uint4*>(r1 + (long)x0c * 512);
            uint4 u11 = *reinterpret_cast<const uint4*>(r1 + (long)x1c * 512);
            float wp = wts[pt];
            pkfma8(hacc, __float2half2_rn(wp * wy0v * wx0v), u00);
            pkfma8(hacc, __float2half2_rn(wp * wy0v * wx1v), u01);
            pkfma8(hacc, __float2half2_rn(wp * wy1v * wx0v), u10);
            pkfma8(hacc, __float2half2_rn(wp * wy1v * wx1v), u11);
        }
        // per-direction f32 rollup (bounds the f16 chain to <=16 pk-fmas)
        acc[0] += __low2float(hacc[0]); acc[1] += __high2float(hacc[0]);
        acc[2] += __low2float(hacc[1]); acc[3] += __high2float(hacc[1]);
        acc[4] += __low2float(hacc[2]); acc[5] += __high2float(hacc[2]);
        acc[6] += __low2float(hacc[3]); acc[7] += __high2float(hacc[3]);
    }
    uint4 o;
    o.x = pack2(acc[0] * 0.5f, acc[1] * 0.5f);
    o.y = pack2(acc[2] * 0.5f, acc[3] * 0.5f);
    o.z = pack2(acc[4] * 0.5f, acc[5] * 0.5f);
    o.w = pack2(acc[6] * 0.5f, acc[7] * 0.5f);
    *reinterpret_cast<uint4*>(tfB + (n0 + ql) * 256 + choff) = o;
}

// ---------------- Spatial v16: v14 + s-pair unroll (4 loads in flight, 1 query/wave) ----------------
// Round-8 lesson: ILP must not cost residency. Two s-samples of the same (c,p) share
// visibility/rx/ry/inv; their 4 y-corner loads are independent and all issue before
// the dependent pk-fmas. Extra live state ~2 uint4 -> VGPR stays under the ~52
// full-residency budget (2500 blocks x 4 waves = 9.8 waves/SIMD needs VGPR <= 52).
__global__ __launch_bounds__(256) void spatial_kernel(const elt* __restrict__ soffB,
                                                      const elt* __restrict__ swlB,
                                                      const void* __restrict__ refcam,
                                                      const void* __restrict__ bmask,
                                                      const elt* __restrict__ imgT,
                                                      const void* __restrict__ img_raw,
                                                      int use_imgT,
                                                      const int* __restrict__ flags,
                                                      elt* __restrict__ sfB) {
    int tid = threadIdx.x;
    int ql = tid >> 6, lane = tid & 63;
    int cxh = lane >> 5;
    int h5 = lane & 31;
    int g = h5 >> 2, c8 = h5 & 3;
    long n0 = (long)blockIdx.x * 4;
    __shared__ float s_soff[4][8][33];
    __shared__ float s_swl[4][144];        // [q][j*9 + g]
    __shared__ float s_ref[4][NC][PP][2];
    __shared__ int   s_vis[4][NC][PP];
    for (int i = tid; i < 4 * 256; i += 256) {
        int q = i >> 8, j = i & 255;
        s_soff[q][j >> 5][j & 31] = h2f(soffB[n0 * 256 + i]);
    }
    for (int i = tid; i < 4 * 128; i += 256) {
        int q = i >> 7, jr = i & 127;
        int gg = jr >> 4, j = jr & 15;
        s_swl[q][j * 9 + gg] = h2f(swlB[n0 * 128 + i]);
    }
    int fdt = flags[0], msz = flags[1];
    if (tid < 4 * 48) {
        int q = tid / 48, r = tid % 48;
        s_ref[q][r >> 3][(r & 7) >> 1][r & 1] =
            load_any(refcam, ((long)(r >> 3) * N_Q + n0 + q) * 8 + (r & 7), fdt);
    }
    // s_vis staging: 96 entries, window [160, 256)
    if (tid >= 160 && tid < 160 + 4 * 24) {
        int tt = tid - 160;
        int q = tt / 24, r = tt % 24; int c = r >> 2, p = r & 3;
        long idx = ((long)c * N_Q + n0 + q) * 4 + p;
        int v;
        if (msz == 1)      v = ((const unsigned char*)bmask)[idx] != 0;
        else if (msz == 2) v = ((const unsigned short*)bmask)[idx] != 0;
        else if (msz == 4) v = ((const unsigned int*)bmask)[idx] != 0u;
        else               v = ((const unsigned long long*)bmask)[idx] != 0ULL;
        s_vis[q][c][p] = v;
    }
    __syncthreads();
    // hoisted softmax numerators (shift-invariant masked softmax)
    float ew[16];
    {
        float lw[16], mx = -3e38f;
        #pragma unroll
        for (int j = 0; j < 16; j++) { lw[j] = s_swl[ql][j * 9 + g]; mx = fmaxf(mx, lw[j]); }
        #pragma unroll
        for (int j = 0; j < 16; j++) ew[j] = __expf(lw[j] - mx);
    }
    float acc[8];
    #pragma unroll
    for (int i = 0; i < 8; i++) acc[i] = 0.f;
    float cnt = 0.f;
    int choff = g * 32 + c8 * 8;
    for (int c = 0; c < NC; c++) {
        int m0 = s_vis[ql][c][0], m1 = s_vis[ql][c][1];
        int m2 = s_vis[ql][c][2], m3 = s_vis[ql][c][3];
        if (!(m0 | m1 | m2 | m3)) continue;
        cnt += 1.f;
        float sum = 0.f;
        #pragma unroll
        for (int j = 0; j < 16; j++)
            sum += s_vis[ql][c][j >> 2] ? ew[j] : 0.f;
        float inv = 1.f / fmaxf(sum, 1e-20f);
        const elt* img = imgT + (long)c * HF * WF * 256 + choff;
        __half2 hz = __floats2half2_rn(0.f, 0.f);
        __half2 hacc[4] = {hz, hz, hz, hz};
        #pragma unroll
        for (int p = 0; p < PP; p++) {
            if (!s_vis[ql][c][p]) continue;
            float rx = s_ref[ql][c][p][0], ry = s_ref[ql][c][p][1];
            #pragma unroll
            for (int s2 = 0; s2 < PS; s2 += 2) {
                // --- sample 0 coords ---
                float wi0 = ew[p * 4 + s2] * inv;
                float u0 = rx + s_soff[ql][g][p * 8 + s2 * 2 + 0];
                float v0 = ry + s_soff[ql][g][p * 8 + s2 * 2 + 1];
                float ix0 = u0 * (float)WF - 0.5f, iy0 = v0 * (float)HF - 0.5f;
                float xf0 = floorf(ix0), yf0 = floorf(iy0);
                int x00 = (int)xf0, y00 = (int)yf0;
                float wx10 = ix0 - xf0, wy10 = iy0 - yf0;
                int xi0 = x00 + cxh;
                float wxa = cxh ? wx10 : (1.f - wx10);
                wxa = ((unsigned)xi0 < WF) ? wxa : 0.f;
                int xc0 = min(max(xi0, 0), WF - 1);
                float ww0 = wi0 * wxa;
                float wy00 = ((unsigned)y00 < HF) ? (1.f - wy10) : 0.f;
                float wy01 = ((unsigned)(y00 + 1) < HF) ? wy10 : 0.f;
                int ya0 = min(max(y00, 0), HF - 1);
                int ya1 = min(max(y00 + 1, 0), HF - 1);
                // --- sample 1 coords ---
                float wi1 = ew[p * 4 + s2 + 1] * inv;
                float u1 = rx + s_soff[ql][g][p * 8 + s2 * 2 + 2];
                float v1 = ry + s_soff[ql][g][p * 8 + s2 * 2 + 3];
                float ix1 = u1 * (float)WF - 0.5f, iy1 = v1 * (float)HF - 0.5f;
                float xf1 = floorf(ix1), yf1 = floorf(iy1);
                int x01 = (int)xf1, y01 = (int)yf1;
                float wx11 = ix1 - xf1, wy11 = iy1 - yf1;
                int xi1 = x01 + cxh;
                float wxb = cxh ? wx11 : (1.f - wx11);
                wxb = ((unsigned)xi1 < WF) ? wxb : 0.f;
                int xc1 = min(max(xi1, 0), WF - 1);
                float ww1 = wi1 * wxb;
                float wy02 = ((unsigned)y01 < HF) ? (1.f - wy11) : 0.f;
                float wy03 = ((unsigned)(y01 + 1) < HF) ? wy11 : 0.f;
                int yb0 = min(max(y01, 0), HF - 1);
                int yb1 = min(max(y01 + 1, 0), HF - 1);
                if (use_imgT) {
                    // 4 independent loads in flight before any dependent fma
                    uint4 a0 = *reinterpret_cast<const uint4*>(img + (long)(ya0 * WF + xc0) * 256);
                    uint4 a1 = *reinterpret_cast<const uint4*>(img + (long)(ya1 * WF + xc0) * 256);
                    uint4 b0 = *reinterpret_cast<const uint4*>(img + (long)(yb0 * WF + xc1) * 256);
                    uint4 b1 = *reinterpret_cast<const uint4*>(img + (long)(yb1 * WF + xc1) * 256);
                    pkfma8(hacc, __float2half2_rn(ww0 * wy00), a0);
                    pkfma8(hacc, __float2half2_rn(ww0 * wy01), a1);
                    pkfma8(hacc, __float2half2_rn(ww1 * wy02), b0);
                    pkfma8(hacc, __float2half2_rn(ww1 * wy03), b1);
                } else {
                    #pragma unroll
                    for (int e = 0; e < 8; e++) {
                        long base = ((long)c * 256 + choff + e) * HF;
                        acc[e] += (ww0 * wy00) * load_any(img_raw, (base + ya0) * WF + xc0, fdt)
                                + (ww0 * wy01) * load_any(img_raw, (base + ya1) * WF + xc0, fdt)
                                + (ww1 * wy02) * load_any(img_raw, (base + yb0) * WF + xc1, fdt)
                                + (ww1 * wy03) * load_any(img_raw, (base + yb1) * WF + xc1, fdt);
                    }
                }
            }
        }
        // per-camera f32 rollup (bounds the f16 chain to <=32 pk-fmas)
        acc[0] += __low2float(hacc[0]); acc[1] += __high2float(hacc[0]);
        acc[2] += __low2float(hacc[1]); acc[3] += __high2float(hacc[1]);
        acc[4] += __low2float(hacc[2]); acc[5] += __high2float(hacc[2]);
        acc[6] += __low2float(hacc[3]); acc[7] += __high2float(hacc[3]);
    }
    // combine the two corner-x halves: lane i and lane i^32 hold same channels
    #pragma unroll
    for (int e = 0; e < 8; e++) acc[e] += __shfl_xor(acc[e], 32);
    float invc = 1.f / fmaxf(cnt, 1.f);
    if (cxh == 0) {
        uint4 o;
        o.x = pack2(acc[0] * invc, acc[1] * invc);
        o.y = pack2(acc[2] * invc, acc[3] * invc);
        o.z = pack2(acc[4] * invc, acc[5] * invc);
        o.w = pack2(acc[6] * invc, acc[7] * invc);
        *reinterpret_cast<uint4*>(sfB + (n0 + ql) * 256 + choff) = o;
    }
}

// f16 element offsets inside the weight region (matrices stored TRANSPOSED [J][K])
#define W_TOFF_W 0
#define W_TOFF_B 65536
#define W_TWT_W  65664
#define W_TWT_B  98432
#define W_TOUT_W 98496
#define W_TOUT_B 164032
#define W_SOFF_W 164288
#define W_SOFF_B 229824
#define W_SWT_W  230080
#define W_SWT_B  262848
#define W_SOUT_W 262976
#define W_SOUT_B 328512
#define W_FFN_W1 328768
#define W_FFN_B1 590912
#define W_FFN_W2 591936
#define W_FFN_B2 854080
#define W_LN1_G  854336
#define W_LN1_B  854592
#define W_LN2_G  854848
#define W_LN2_B  855104
#define W_LN3_G  855360
#define W_LN3_B  855616

// byte offsets in workspace (total ~35.6 MB)
#define OB_WGT   0
#define OB_FLAGS 1711744
#define OB_AI    1712640
#define OB_TF    11952640
#define OB_X     17072640
#define OB_T4    27312640
#define OB_IMG   31152640
#define WS_NEED_IMG 35576320ULL

extern "C" void kernel_launch(void* const* d_in, const int* in_sizes, int n_in,
                              void* d_out, int out_size, void* d_ws, size_t ws_size,
                              hipStream_t stream) {
    char* W8 = (char*)d_ws;
    elt*   wgt   = (elt*)(W8 + OB_WGT);
    int*   flags = (int*)(W8 + OB_FLAGS);
    elt*   ai    = (elt*)(W8 + OB_AI);                  // N x 512, pb | q1
    elt*   q2B   = ai;                                  // N x 256 (after temporal)
    elt*   sfB   = (elt*)(W8 + OB_AI + 5120000);        // N x 256
    elt*   tfB   = (elt*)(W8 + OB_TF);                  // N x 256
    elt*   soffB = tfB;                                 // N x 256 (after t_out gemm)
    float* x     = (float*)(W8 + OB_X);                 // N x 256 f32 trunk
    elt*   toffB = (elt*)(W8 + OB_T4);                  // N x 128
    elt*   twlB  = (elt*)(W8 + OB_T4 + 2560000);        // N x 64
    elt*   swlB  = toffB;                               // N x 128 (after temporal)
    elt*   imgT  = (elt*)(W8 + OB_IMG);                 // NC*HF*WF*256
    int use_imgT = (ws_size >= WS_NEED_IMG) ? 1 : 0;

    detect_kernel<<<1, 256, 0, stream>>>(d_in[22], d_in[28], flags);

    {   // unified prep: 8 transposes + 14 flat cvts + img transpose
        PrepDesc pd;
        const int tsrc[8] = {6, 8, 10, 12, 14, 16, 18, 20};
        const int toff[8] = {W_TOFF_W, W_TWT_W, W_TOUT_W, W_SOFF_W, W_SWT_W, W_SOUT_W,
                             W_FFN_W1, W_FFN_W2};
        const int tR[8] = {512, 512, 256, 256, 256, 256, 256, 1024};
        const int tC[8] = {128, 64, 256, 256, 128, 256, 1024, 256};
        const int fsrc[14] = {7, 9, 11, 13, 15, 17, 19, 21, 22, 23, 24, 25, 26, 27};
        const int foff[14] = {W_TOFF_B, W_TWT_B, W_TOUT_B, W_SOFF_B, W_SWT_B, W_SOUT_B,
                              W_FFN_B1, W_FFN_B2, W_LN1_G, W_LN1_B, W_LN2_G, W_LN2_B,
                              W_LN3_G, W_LN3_B};
        const int fcnt[14] = {128, 64, 256, 256, 128, 256, 1024, 256, 256, 256, 256, 256, 256, 256};
        int a = 0, blk = 0;
        for (int i = 0; i < 8; i++, a++) {
            pd.src[a] = d_in[tsrc[i]]; pd.dst_off[a] = toff[i];
            pd.count[a] = tR[i] * tC[i]; pd.R[a] = tR[i]; pd.C[a] = tC[i];
            pd.type[a] = 1; pd.blk_start[a] = blk; blk += (pd.count[a] + 255) / 256;
        }
        for (int i = 0; i < 14; i++, a++) {
            pd.src[a] = d_in[fsrc[i]]; pd.dst_off[a] = foff[i];
            pd.count[a] = fcnt[i]; pd.R[a] = 0; pd.C[a] = 0;
            pd.type[a] = 0; pd.blk_start[a] = blk; blk += (pd.count[a] + 255) / 256;
        }
        pd.src[a] = d_in[2]; pd.dst_off[a] = 0;
        pd.count[a] = use_imgT ? NC * HF * WF * 256 : 0;
        pd.R[a] = 0; pd.C[a] = 0; pd.type[a] = 2; pd.blk_start[a] = blk;
        blk += (pd.count[a] + 255) / 256;
        pd.blk_start[NP] = blk;
        prep_kernel<<<blk, 256, 0, stream>>>(pd, wgt, imgT, flags);
    }

    ln12_kernel<<<5000, 256, 0, stream>>>(d_in[1], d_in[0], flags,
                                          wgt + W_LN1_G, wgt + W_LN1_B, ai);
    gemm_dual<512, 128, 64><<<dim3(313, 3), 256, 0, stream>>>(ai,
        wgt + W_TOFF_W, wgt + W_TOFF_B, T_RAD, toffB,
        wgt + W_TWT_W, wgt + W_TWT_B, twlB);
    temporal_kernel<<<1250, 256, 0, stream>>>(ai, toffB, twlB, d_in[3], d_in[5], flags, tfB);
    gemm_mfma<256, 256, 2><<<dim3(313, 4), 256, 0, stream>>>(tfB, wgt + W_TOUT_W, wgt + W_TOUT_B,
        x, d_in[0], nullptr, flags);
    ln_kernel<<<2500, 256, 0, stream>>>(x, wgt + W_LN2_G, wgt + W_LN2_B, q2B);
    gemm_dual<256, 256, 128><<<dim3(313, 6), 256, 0, stream>>>(q2B,
        wgt + W_SOFF_W, wgt + W_SOFF_B, S_RAD, soffB,
        wgt + W_SWT_W, wgt + W_SWT_B, swlB);
    spatial_kernel<<<2500, 256, 0, stream>>>(soffB, swlB, d_in[4], d_in[28], imgT, d_in[2],
                                             use_imgT, flags, sfB);
    gemm_mfma<256, 256, 3><<<dim3(313, 4), 256, 0, stream>>>(sfB, wgt + W_SOUT_W, wgt + W_SOUT_B,
        x, nullptr, x, flags);
    ffn_mfma<<<625, 256, 0, stream>>>(x, wgt + W_LN3_G, wgt + W_LN3_B,
                                      wgt + W_FFN_W1, wgt + W_FFN_B1,
                                      wgt + W_FFN_W2, wgt + W_FFN_B2, d_out, flags);
}